// Round 1
// baseline (315.534 us; speedup 1.0000x reference)
//
#include <hip/hip_runtime.h>

// LinearAttention fused pipeline for MI355X (gfx950) — round 5.
// Key change vs r4: kill the per-lane scalar-LDS+f2bf repack in K2.
// K1 already builds the bf16 B-fragments; it now stores them once per tile
// to a swizzled bf16 x^T tile buffer (xt, 33.5 MB in ws). K2 stages those
// tiles linearly via global_load_lds and reads B-frags with conflict-free
// swizzled ds_read_b128 (zero converts, zero scalar LDS reads). K1's own
// f32 tile reads get a source-preswizzle to kill their 4-way bank conflict.
// K2 LDS 60->44 KB, grid 512->1024 (TPB 4->2) for 3 blocks/CU.
// Numerics bit-identical to r4 (same RNE f2bf applied at the same point).
//
// ws: ctx_u[32][4][32][32] f32 | Z[32][128] f32 | stats[32][2] f32 |
//     wb 4x16384 bf16 | xt 32x64 tiles x 16384 B (bf16 x^T, st-swizzled)

#define B_   32
#define C_   128
#define N_   4096
#define H_   4
#define D_   32
#define HID  128
#define NB   64
#define TPB  4        // n-tiles per block (K1)
#define NSTRIP 16     // strips per batch, K1 (NSTRIP*TPB*NB == N_)
#define TPB2   2      // n-tiles per block (K2)
#define NSTRIP2 32    // strips per batch, K2
#define STV  72       // ek/v row stride (shorts)
#define STA  136      // eqT/attnT row stride (shorts)
#define SCT  40       // ctxT row stride (shorts)
#define SCALE 0.1767766952966369f
#define EPS  1e-5f

typedef __attribute__((ext_vector_type(8))) short short8;
typedef __attribute__((ext_vector_type(4))) short short4v;
typedef __attribute__((ext_vector_type(4))) float floatx4;

__device__ __forceinline__ short f2bf(float f) {   // RNE fp32 -> bf16
  unsigned u = __float_as_uint(f);
  u += 0x7FFFu + ((u >> 16) & 1u);
  return (short)(u >> 16);
}
__device__ __forceinline__ float bf2f(short h) {
  return __uint_as_float(((unsigned)(unsigned short)h) << 16);
}
__device__ __forceinline__ void gload_lds16(const float* g, void* l) {
  __builtin_amdgcn_global_load_lds(
      (const __attribute__((address_space(1))) unsigned int*)g,
      (__attribute__((address_space(3))) unsigned int*)l, 16, 0, 0);
}
// K1 natx (f32 [c][n]) bank-conflict fix: XOR n bits 3-4 with c bits 3-4.
// Applied on the global SOURCE address (LDS dest stays linear for gload_lds)
// and on the read index — same involution both sides.
__device__ __forceinline__ int swzn(int c) {
  return (((c >> 3) & 1) << 4) | (((c >> 4) & 1) << 3);
}

// ---------------------------------------------------------------- K0: weights -> bf16
__global__ __launch_bounds__(256) void k_wcast(
    const float* __restrict__ Wq, const float* __restrict__ Wk,
    const float* __restrict__ Wv, const float* __restrict__ Wo,
    short* __restrict__ wb) {
  const int i = blockIdx.x * 256 + threadIdx.x;   // 0..16383, 4 elems each
  const float* srcs[4] = {Wq, Wk, Wv, Wo};
#pragma unroll
  for (int m = 0; m < 4; ++m) {
    floatx4 a = ((const floatx4*)srcs[m])[i];
    short4v s = { f2bf(a[0]), f2bf(a[1]), f2bf(a[2]), f2bf(a[3]) };
    ((short4v*)(wb + m * 16384))[i] = s;
  }
}

// ---------------------------------------------------------------- K1: k,v proj + ctx/Z (+ xt store)
__global__ __launch_bounds__(256, 2) void k_kv_ctx(
    const float* __restrict__ x, const short* __restrict__ Wkb,
    const short* __restrict__ Wvb, float* __restrict__ ctx_u,
    float* __restrict__ Zsum, short* __restrict__ xt) {
  __shared__ float natx[C_ * NB];        // [128][64] f32, 32 KB, n-preswizzled
  __shared__ short ekbuf[C_ * STV];      // 18 KB
  __shared__ short vbuf [C_ * STV];      // 18 KB
  const int tid = threadIdx.x;
  const int w = tid >> 6, L = tid & 63, l15 = tid & 15, q4 = (tid & 63) >> 4;
  const int b = blockIdx.x / NSTRIP;
  const int strip = blockIdx.x % NSTRIP;
  const float* xb = x + (size_t)b * C_ * N_;
  const int szr = ((q4 & 1) << 4) | ((q4 & 2) << 2);  // == swzn(c) for c-bits(3,4)=q4
  const int szw = (l15 & 7) << 3;                     // xt tile swizzle (shorts)

  // register-resident A-frags for both weights
  short8 ak[2][4], av[2][4];
#pragma unroll
  for (int mt = 0; mt < 2; ++mt)
#pragma unroll
    for (int ks = 0; ks < 4; ++ks) {
      ak[mt][ks] = *(const short8*)&Wkb[(w * 32 + mt * 16 + l15) * C_ + ks * 32 + q4 * 8];
      av[mt][ks] = *(const short8*)&Wvb[(w * 32 + mt * 16 + l15) * C_ + ks * 32 + q4 * 8];
    }

  const floatx4 z4 = {0.f, 0.f, 0.f, 0.f};
  floatx4 ca[2][2] = {{z4, z4}, {z4, z4}};   // ctx accumulator across tiles
  float zreg[2][4] = {{0.f,0.f,0.f,0.f},{0.f,0.f,0.f,0.f}};

  // stage tile 0 (source n preswizzled; LDS dest linear)
#pragma unroll
  for (int i = 0; i < 8; ++i) {
    const int c = w * 32 + i * 4 + (L >> 4);
    gload_lds16(xb + (size_t)c * N_ + (size_t)(strip * TPB) * NB + (((L & 15) * 4) ^ swzn(c)),
                (char*)natx + ((w * 32 + i * 4) * NB + L * 4) * 4);
  }

  for (int t = 0; t < TPB; ++t) {
    __syncthreads();   // b1: stage(t) visible

    floatx4 acck[2][4], accv[2][4];
#pragma unroll
    for (int mt = 0; mt < 2; ++mt)
#pragma unroll
      for (int nt = 0; nt < 4; ++nt) { acck[mt][nt] = z4; accv[mt][nt] = z4; }

    // k and v GEMMs; B-frags built from preswizzled LDS (2-way banks = free)
    short8 myB[4];
#pragma unroll
    for (int ks = 0; ks < 4; ++ks) {
      short8 Bf[4];
#pragma unroll
      for (int nt = 0; nt < 4; ++nt) {
        short8 s;
#pragma unroll
        for (int j = 0; j < 8; ++j)
          s[j] = f2bf(natx[(ks * 32 + q4 * 8 + j) * NB + ((nt * 16 + l15) ^ szr)]);
        Bf[nt] = s;
      }
      if (ks == w) {      // this wave owns this c-quarter of the xt tile
        myB[0] = Bf[0]; myB[1] = Bf[1]; myB[2] = Bf[2]; myB[3] = Bf[3];
      }
#pragma unroll
      for (int mt = 0; mt < 2; ++mt)
#pragma unroll
        for (int nt = 0; nt < 4; ++nt) {
          acck[mt][nt] = __builtin_amdgcn_mfma_f32_16x16x32_bf16(ak[mt][ks], Bf[nt], acck[mt][nt], 0, 0, 0);
          accv[mt][nt] = __builtin_amdgcn_mfma_f32_16x16x32_bf16(av[mt][ks], Bf[nt], accv[mt][nt], 0, 0, 0);
        }
    }
    __syncthreads();   // b2: natx reads done -> restage allowed

    // prefetch stage(t+1) — flies during the wave-local phase below
    if (t + 1 < TPB) {
#pragma unroll
      for (int i = 0; i < 8; ++i) {
        const int c = w * 32 + i * 4 + (L >> 4);
        gload_lds16(xb + (size_t)c * N_ + (size_t)(strip * TPB + t + 1) * NB + (((L & 15) * 4) ^ swzn(c)),
                    (char*)natx + ((w * 32 + i * 4) * NB + L * 4) * 4);
      }
    }

    // store this tile's bf16 x^T fragments (swizzled image, linear-stageable
    // by K2's global_load_lds). Fire-and-forget; drains under next phases.
    if (xt) {
      short* xtb = xt + ((size_t)(b * 64 + strip * TPB + t)) * 8192;
#pragma unroll
      for (int nt = 0; nt < 4; ++nt)
        *(short8*)&xtb[(nt * 16 + l15) * C_ + ((w * 32 + q4 * 8) ^ szw)] = myB[nt];
    }

    // exp(k) + Z partial accumulation in registers
#pragma unroll
    for (int mt = 0; mt < 2; ++mt)
#pragma unroll
      for (int nt = 0; nt < 4; ++nt)
#pragma unroll
        for (int r = 0; r < 4; ++r)
          acck[mt][nt][r] = __expf(acck[mt][nt][r]);
#pragma unroll
    for (int mt = 0; mt < 2; ++mt)
#pragma unroll
      for (int r = 0; r < 4; ++r)
        zreg[mt][r] += acck[mt][0][r] + acck[mt][1][r] + acck[mt][2][r] + acck[mt][3][r];

    // pack ek, v into wave-local LDS rows (in-wave DS ordering, no barrier)
#pragma unroll
    for (int mt = 0; mt < 2; ++mt)
#pragma unroll
      for (int nt = 0; nt < 4; ++nt)
#pragma unroll
        for (int r = 0; r < 4; ++r) {
          ekbuf[(w * 32 + mt * 16 + q4 * 4 + r) * STV + nt * 16 + l15] = f2bf(acck[mt][nt][r]);
          vbuf [(w * 32 + mt * 16 + q4 * 4 + r) * STV + nt * 16 + l15] = f2bf(accv[mt][nt][r]);
        }

    // ctx partial via MFMA (wave-local rows), accumulates across tiles
#pragma unroll
    for (int ks = 0; ks < 2; ++ks) {
      short8 ae[2], be[2];
#pragma unroll
      for (int mt = 0; mt < 2; ++mt)
        ae[mt] = *(const short8*)&ekbuf[(w * 32 + mt * 16 + l15) * STV + ks * 32 + q4 * 8];
#pragma unroll
      for (int nt = 0; nt < 2; ++nt)
        be[nt] = *(const short8*)&vbuf[(w * 32 + nt * 16 + l15) * STV + ks * 32 + q4 * 8];
#pragma unroll
      for (int mt = 0; mt < 2; ++mt)
#pragma unroll
        for (int nt = 0; nt < 2; ++nt)
          ca[mt][nt] = __builtin_amdgcn_mfma_f32_16x16x32_bf16(ae[mt], be[nt], ca[mt][nt], 0, 0, 0);
    }
  }

  // Z: reduce over l15, one atomic per row
#pragma unroll
  for (int mt = 0; mt < 2; ++mt)
#pragma unroll
    for (int r = 0; r < 4; ++r) {
      float s = zreg[mt][r];
      s += __shfl_xor(s, 1); s += __shfl_xor(s, 2);
      s += __shfl_xor(s, 4); s += __shfl_xor(s, 8);
      if (l15 == 0) atomicAdd(&Zsum[b * HID + w * 32 + mt * 16 + q4 * 4 + r], s);
    }

  // ctx atomics (once per block)
  float* cb = &ctx_u[((size_t)b * H_ + w) * (D_ * D_)];
#pragma unroll
  for (int mt = 0; mt < 2; ++mt)
#pragma unroll
    for (int nt = 0; nt < 2; ++nt)
#pragma unroll
      for (int r = 0; r < 4; ++r)
        atomicAdd(&cb[(mt * 16 + q4 * 4 + r) * D_ + nt * 16 + l15], ca[mt][nt][r]);
}

// ---------------------------------------------------------------- K2: q proj + attn + Wo + stats (xt consumer)
__global__ __launch_bounds__(256, 3) void k_q_attn_o(
    const short* __restrict__ xt, const short* __restrict__ Wqb,
    const short* __restrict__ Wob, const float* __restrict__ bo,
    const float* __restrict__ ctx_u, const float* __restrict__ Zsum,
    float* __restrict__ outp, float* __restrict__ stats) {
  __shared__ short natx2[NB * C_];    // 16 KB bf16 x^T tile, st-swizzled
  __shared__ short qat[NB * STA];     // eq^T then attn^T, 17 KB
  __shared__ short ctxT[HID * SCT];   // 10 KB
  const int tid = threadIdx.x;
  const int w = tid >> 6, L = tid & 63, l15 = tid & 15, q4 = (tid & 63) >> 4;
  const int b = blockIdx.x / NSTRIP2;
  const int strip = blockIdx.x % NSTRIP2;
  const int szw = (l15 & 7) << 3;
  (void)L;

  // stage tile 0 (linear copy of the swizzled tile image), then fill ctxT
  {
    const float* src = (const float*)(xt + (size_t)(b * 64 + strip * TPB2) * 8192);
#pragma unroll
    for (int i = 0; i < 4; ++i)
      gload_lds16(src + tid * 4 + i * 1024, (char*)natx2 + tid * 16 + i * 4096);
  }
#pragma unroll
  for (int i = 0; i < 16; ++i) {
    const int idx = tid + i * 256;               // h*1024 + d*32 + e
    float v = ctx_u[(size_t)b * (H_ * D_ * D_) + idx] *
              __builtin_amdgcn_rcpf(Zsum[b * HID + (idx >> 5)]);
    ctxT[((idx >> 10) * 32 + (idx & 31)) * SCT + ((idx >> 5) & 31)] = f2bf(v);
  }

  // register-resident A-frags for Wq and Wo
  short8 aq[2][4], ao[2][4];
#pragma unroll
  for (int mt = 0; mt < 2; ++mt)
#pragma unroll
    for (int ks = 0; ks < 4; ++ks) {
      aq[mt][ks] = *(const short8*)&Wqb[(w * 32 + mt * 16 + l15) * C_ + ks * 32 + q4 * 8];
      ao[mt][ks] = *(const short8*)&Wob[(w * 32 + mt * 16 + l15) * HID + ks * 32 + q4 * 8];
    }

  const floatx4 z4 = {0.f, 0.f, 0.f, 0.f};
  float s1 = 0.f, s2 = 0.f;

  for (int t = 0; t < TPB2; ++t) {
    const int n0 = (strip * TPB2 + t) * NB;
    __syncthreads();   // b1: stage(t) + (t==0) ctxT visible

    // q = Wq @ x — B-frags are direct swizzled ds_read_b128, no converts
    floatx4 acc[2][4];
#pragma unroll
    for (int mt = 0; mt < 2; ++mt)
#pragma unroll
      for (int nt = 0; nt < 4; ++nt) acc[mt][nt] = z4;
#pragma unroll
    for (int ks = 0; ks < 4; ++ks) {
      short8 Bf[4];
#pragma unroll
      for (int nt = 0; nt < 4; ++nt)
        Bf[nt] = *(const short8*)&natx2[(nt * 16 + l15) * C_ + ((ks * 32 + q4 * 8) ^ szw)];
#pragma unroll
      for (int mt = 0; mt < 2; ++mt)
#pragma unroll
        for (int nt = 0; nt < 4; ++nt)
          acc[mt][nt] = __builtin_amdgcn_mfma_f32_16x16x32_bf16(aq[mt][ks], Bf[nt], acc[mt][nt], 0, 0, 0);
    }
    __syncthreads();   // b2: natx2 reads done -> restage allowed

    // prefetch stage(t+1)
    if (t + 1 < TPB2) {
      const float* src = (const float*)(xt + (size_t)(b * 64 + strip * TPB2 + t + 1) * 8192);
#pragma unroll
      for (int i = 0; i < 4; ++i)
        gload_lds16(src + tid * 4 + i * 1024, (char*)natx2 + tid * 16 + i * 4096);
    }

    // exp(q); per-column softmax denom via shuffle
#pragma unroll
    for (int mt = 0; mt < 2; ++mt)
#pragma unroll
      for (int nt = 0; nt < 4; ++nt)
#pragma unroll
        for (int r = 0; r < 4; ++r)
          acc[mt][nt][r] = __expf(acc[mt][nt][r]);
    float inv[4];
#pragma unroll
    for (int nt = 0; nt < 4; ++nt) {
      float s = 0.f;
#pragma unroll
      for (int mt = 0; mt < 2; ++mt)
#pragma unroll
        for (int r = 0; r < 4; ++r) s += acc[mt][nt][r];
      s += __shfl_xor(s, 16); s += __shfl_xor(s, 32);
      inv[nt] = SCALE * __builtin_amdgcn_rcpf(s);
    }

    // scaled eq^T into qat (wave-local columns)
#pragma unroll
    for (int mt = 0; mt < 2; ++mt)
#pragma unroll
      for (int nt = 0; nt < 4; ++nt) {
        short4v pk = { f2bf(acc[mt][nt][0] * inv[nt]), f2bf(acc[mt][nt][1] * inv[nt]),
                       f2bf(acc[mt][nt][2] * inv[nt]), f2bf(acc[mt][nt][3] * inv[nt]) };
        *(short4v*)&qat[(nt * 16 + l15) * STA + w * 32 + mt * 16 + q4 * 4] = pk;
      }

    // attn: out[e][n] = sum_d ctxT[e][d] * eq[d][n]   (wave-local)
    {
      floatx4 aacc[2][4];
#pragma unroll
      for (int mt = 0; mt < 2; ++mt)
#pragma unroll
        for (int nt = 0; nt < 4; ++nt) aacc[mt][nt] = z4;
      short8 ae[2];
#pragma unroll
      for (int mt = 0; mt < 2; ++mt)
        ae[mt] = *(const short8*)&ctxT[(w * 32 + mt * 16 + l15) * SCT + q4 * 8];
#pragma unroll
      for (int nt = 0; nt < 4; ++nt) {
        short8 bq = *(const short8*)&qat[(nt * 16 + l15) * STA + w * 32 + q4 * 8];
#pragma unroll
        for (int mt = 0; mt < 2; ++mt)
          aacc[mt][nt] = __builtin_amdgcn_mfma_f32_16x16x32_bf16(ae[mt], bq, aacc[mt][nt], 0, 0, 0);
      }
      // attn^T over eq^T (same wave-local columns)
#pragma unroll
      for (int nt = 0; nt < 4; ++nt)
#pragma unroll
        for (int mt = 0; mt < 2; ++mt) {
          short4v pk = { f2bf(aacc[mt][nt][0]), f2bf(aacc[mt][nt][1]),
                         f2bf(aacc[mt][nt][2]), f2bf(aacc[mt][nt][3]) };
          *(short4v*)&qat[(nt * 16 + l15) * STA + w * 32 + mt * 16 + q4 * 4] = pk;
        }
    }
    __syncthreads();   // b3: attn^T visible to all waves

    // out_pre = Wo @ attn + bo
    floatx4 oacc[2][4];
#pragma unroll
    for (int mt = 0; mt < 2; ++mt)
#pragma unroll
      for (int nt = 0; nt < 4; ++nt) oacc[mt][nt] = z4;
#pragma unroll
    for (int ks = 0; ks < 4; ++ks) {
      short8 bf8[4];
#pragma unroll
      for (int nt = 0; nt < 4; ++nt)
        bf8[nt] = *(const short8*)&qat[(nt * 16 + l15) * STA + ks * 32 + q4 * 8];
#pragma unroll
      for (int mt = 0; mt < 2; ++mt)
#pragma unroll
        for (int nt = 0; nt < 4; ++nt)
          oacc[mt][nt] = __builtin_amdgcn_mfma_f32_16x16x32_bf16(ao[mt][ks], bf8[nt], oacc[mt][nt], 0, 0, 0);
    }

    // epilogue: +bo, store, accumulate stats in registers
#pragma unroll
    for (int mt = 0; mt < 2; ++mt) {
      const int rowbase = w * 32 + mt * 16 + q4 * 4;
      const floatx4 bo4 = *(const floatx4*)&bo[rowbase];
#pragma unroll
      for (int nt = 0; nt < 4; ++nt) {
        const int n = n0 + nt * 16 + l15;
#pragma unroll
        for (int r = 0; r < 4; ++r) {
          float vv = oacc[mt][nt][r] + bo4[r];
          outp[(size_t)b * (C_ * N_) + (size_t)(rowbase + r) * N_ + n] = vv;
          s1 += vv; s2 += vv * vv;
        }
      }
    }
  }

  // stats: wave reduce + one atomic pair per wave
#pragma unroll
  for (int m = 1; m < 64; m <<= 1) {
    s1 += __shfl_xor(s1, m);
    s2 += __shfl_xor(s2, m);
  }
  if ((tid & 63) == 0) {
    atomicAdd(&stats[b * 2 + 0], s1);
    atomicAdd(&stats[b * 2 + 1], s2);
  }
}

// ---------------------------------------------------------------- K2 legacy (ws too small): r4 kernel verbatim
__global__ __launch_bounds__(256, 2) void k_q_attn_o_legacy(
    const float* __restrict__ x, const short* __restrict__ Wqb,
    const short* __restrict__ Wob, const float* __restrict__ bo,
    const float* __restrict__ ctx_u, const float* __restrict__ Zsum,
    float* __restrict__ outp, float* __restrict__ stats) {
  __shared__ float natx[C_ * NB];
  __shared__ short qat[NB * STA];
  __shared__ short ctxT[HID * SCT];
  const int tid = threadIdx.x;
  const int w = tid >> 6, L = tid & 63, l15 = tid & 15, q4 = (tid & 63) >> 4;
  const int b = blockIdx.x / NSTRIP;
  const int strip = blockIdx.x % NSTRIP;
  const float* xb = x + (size_t)b * C_ * N_;

#pragma unroll
  for (int i = 0; i < 8; ++i) {
    const int c = w * 32 + i * 4 + (L >> 4);
    gload_lds16(xb + (size_t)c * N_ + (size_t)(strip * TPB) * NB + (L & 15) * 4,
                (char*)natx + ((w * 32 + i * 4) * NB + L * 4) * 4);
  }
#pragma unroll
  for (int i = 0; i < 16; ++i) {
    const int idx = tid + i * 256;
    float v = ctx_u[(size_t)b * (H_ * D_ * D_) + idx] *
              __builtin_amdgcn_rcpf(Zsum[b * HID + (idx >> 5)]);
    ctxT[((idx >> 10) * 32 + (idx & 31)) * SCT + ((idx >> 5) & 31)] = f2bf(v);
  }

  short8 aq[2][4], ao[2][4];
#pragma unroll
  for (int mt = 0; mt < 2; ++mt)
#pragma unroll
    for (int ks = 0; ks < 4; ++ks) {
      aq[mt][ks] = *(const short8*)&Wqb[(w * 32 + mt * 16 + l15) * C_ + ks * 32 + q4 * 8];
      ao[mt][ks] = *(const short8*)&Wob[(w * 32 + mt * 16 + l15) * HID + ks * 32 + q4 * 8];
    }

  const floatx4 z4 = {0.f, 0.f, 0.f, 0.f};
  float s1 = 0.f, s2 = 0.f;

  for (int t = 0; t < TPB; ++t) {
    const int n0 = (strip * TPB + t) * NB;
    __syncthreads();

    floatx4 acc[2][4];
#pragma unroll
    for (int mt = 0; mt < 2; ++mt)
#pragma unroll
      for (int nt = 0; nt < 4; ++nt) acc[mt][nt] = z4;
#pragma unroll
    for (int ks = 0; ks < 4; ++ks) {
      short8 Bf[4];
#pragma unroll
      for (int nt = 0; nt < 4; ++nt) {
        short8 s;
#pragma unroll
        for (int j = 0; j < 8; ++j)
          s[j] = f2bf(natx[(ks * 32 + q4 * 8 + j) * NB + nt * 16 + l15]);
        Bf[nt] = s;
      }
#pragma unroll
      for (int mt = 0; mt < 2; ++mt)
#pragma unroll
        for (int nt = 0; nt < 4; ++nt)
          acc[mt][nt] = __builtin_amdgcn_mfma_f32_16x16x32_bf16(aq[mt][ks], Bf[nt], acc[mt][nt], 0, 0, 0);
    }
    __syncthreads();

    if (t + 1 < TPB) {
#pragma unroll
      for (int i = 0; i < 8; ++i) {
        const int c = w * 32 + i * 4 + (L >> 4);
        gload_lds16(xb + (size_t)c * N_ + (size_t)(n0 + NB) + (L & 15) * 4,
                    (char*)natx + ((w * 32 + i * 4) * NB + L * 4) * 4);
      }
    }

#pragma unroll
    for (int mt = 0; mt < 2; ++mt)
#pragma unroll
      for (int nt = 0; nt < 4; ++nt)
#pragma unroll
        for (int r = 0; r < 4; ++r)
          acc[mt][nt][r] = __expf(acc[mt][nt][r]);
    float inv[4];
#pragma unroll
    for (int nt = 0; nt < 4; ++nt) {
      float s = 0.f;
#pragma unroll
      for (int mt = 0; mt < 2; ++mt)
#pragma unroll
        for (int r = 0; r < 4; ++r) s += acc[mt][nt][r];
      s += __shfl_xor(s, 16); s += __shfl_xor(s, 32);
      inv[nt] = SCALE * __builtin_amdgcn_rcpf(s);
    }

#pragma unroll
    for (int mt = 0; mt < 2; ++mt)
#pragma unroll
      for (int nt = 0; nt < 4; ++nt) {
        short4v pk = { f2bf(acc[mt][nt][0] * inv[nt]), f2bf(acc[mt][nt][1] * inv[nt]),
                       f2bf(acc[mt][nt][2] * inv[nt]), f2bf(acc[mt][nt][3] * inv[nt]) };
        *(short4v*)&qat[(nt * 16 + l15) * STA + w * 32 + mt * 16 + q4 * 4] = pk;
      }

    {
      floatx4 aacc[2][4];
#pragma unroll
      for (int mt = 0; mt < 2; ++mt)
#pragma unroll
        for (int nt = 0; nt < 4; ++nt) aacc[mt][nt] = z4;
      short8 ae[2];
#pragma unroll
      for (int mt = 0; mt < 2; ++mt)
        ae[mt] = *(const short8*)&ctxT[(w * 32 + mt * 16 + l15) * SCT + q4 * 8];
#pragma unroll
      for (int nt = 0; nt < 4; ++nt) {
        short8 bq = *(const short8*)&qat[(nt * 16 + l15) * STA + w * 32 + q4 * 8];
#pragma unroll
        for (int mt = 0; mt < 2; ++mt)
          aacc[mt][nt] = __builtin_amdgcn_mfma_f32_16x16x32_bf16(ae[mt], bq, aacc[mt][nt], 0, 0, 0);
      }
#pragma unroll
      for (int nt = 0; nt < 4; ++nt)
#pragma unroll
        for (int mt = 0; mt < 2; ++mt) {
          short4v pk = { f2bf(aacc[mt][nt][0]), f2bf(aacc[mt][nt][1]),
                         f2bf(aacc[mt][nt][2]), f2bf(aacc[mt][nt][3]) };
          *(short4v*)&qat[(nt * 16 + l15) * STA + w * 32 + mt * 16 + q4 * 4] = pk;
        }
    }
    __syncthreads();

    floatx4 oacc[2][4];
#pragma unroll
    for (int mt = 0; mt < 2; ++mt)
#pragma unroll
      for (int nt = 0; nt < 4; ++nt) oacc[mt][nt] = z4;
#pragma unroll
    for (int ks = 0; ks < 4; ++ks) {
      short8 bf8[4];
#pragma unroll
      for (int nt = 0; nt < 4; ++nt)
        bf8[nt] = *(const short8*)&qat[(nt * 16 + l15) * STA + ks * 32 + q4 * 8];
#pragma unroll
      for (int mt = 0; mt < 2; ++mt)
#pragma unroll
        for (int nt = 0; nt < 4; ++nt)
          oacc[mt][nt] = __builtin_amdgcn_mfma_f32_16x16x32_bf16(ao[mt][ks], bf8[nt], oacc[mt][nt], 0, 0, 0);
    }

#pragma unroll
    for (int mt = 0; mt < 2; ++mt) {
      const int rowbase = w * 32 + mt * 16 + q4 * 4;
      const floatx4 bo4 = *(const floatx4*)&bo[rowbase];
#pragma unroll
      for (int nt = 0; nt < 4; ++nt) {
        const int n = n0 + nt * 16 + l15;
#pragma unroll
        for (int r = 0; r < 4; ++r) {
          float vv = oacc[mt][nt][r] + bo4[r];
          outp[(size_t)b * (C_ * N_) + (size_t)(rowbase + r) * N_ + n] = vv;
          s1 += vv; s2 += vv * vv;
        }
      }
    }
  }

#pragma unroll
  for (int m = 1; m < 64; m <<= 1) {
    s1 += __shfl_xor(s1, m);
    s2 += __shfl_xor(s2, m);
  }
  if ((tid & 63) == 0) {
    atomicAdd(&stats[b * 2 + 0], s1);
    atomicAdd(&stats[b * 2 + 1], s2);
  }
}

// ---------------------------------------------------------------- K3: GroupNorm
__global__ __launch_bounds__(256) void k_gnorm(
    float* __restrict__ outp, const float* __restrict__ stats,
    const float* __restrict__ gnw, const float* __restrict__ gnb) {
  const int b = blockIdx.x >> 6;
  const int blk = blockIdx.x & 63;
  const float M = (float)(C_ * N_);
  const float mu = stats[b * 2 + 0] / M;
  const float var = stats[b * 2 + 1] / M - mu * mu;
  const float rs = rsqrtf(var + EPS);
  floatx4* p = (floatx4*)(outp + (size_t)b * (C_ * N_) + (size_t)blk * 8192);
  const int tid = threadIdx.x;
#pragma unroll
  for (int i = 0; i < 8; ++i) {
    const int idx = tid + i * 256;
    const int fl = blk * 8192 + idx * 4;
    const int c = fl >> 12;
    const float wgt = gnw[c] * rs;
    const float bia = gnb[c] - mu * wgt;
    floatx4 v = p[idx];
    v[0] = v[0] * wgt + bia;
    v[1] = v[1] * wgt + bia;
    v[2] = v[2] * wgt + bia;
    v[3] = v[3] * wgt + bia;
    p[idx] = v;
  }
}

// ---------------------------------------------------------------- launch
extern "C" void kernel_launch(void* const* d_in, const int* in_sizes, int n_in,
                              void* d_out, int out_size, void* d_ws, size_t ws_size,
                              hipStream_t stream) {
  (void)in_sizes; (void)n_in; (void)out_size;
  const float* x   = (const float*)d_in[0];
  const float* Wq  = (const float*)d_in[1];
  const float* Wk  = (const float*)d_in[2];
  const float* Wv  = (const float*)d_in[3];
  const float* Wo  = (const float*)d_in[4];
  const float* bo  = (const float*)d_in[5];
  const float* gnw = (const float*)d_in[6];
  const float* gnb = (const float*)d_in[7];
  float* outp  = (float*)d_out;
  float* ctx_u = (float*)d_ws;                       // 131072 f
  float* Zsum  = ctx_u + B_ * H_ * D_ * D_;          // 4096 f
  float* stats = Zsum + B_ * HID;                    // 64 f
  short* wb    = (short*)(stats + B_ * 2);           // 4 x 16384 bf16
  short* xt    = (short*)((char*)d_ws + 672000);     // 32*64 tiles x 16384 B
  const int fast = ws_size >= (size_t)34226432;      // 672000 + 33554432
  const size_t zbytes = (size_t)(B_ * H_ * D_ * D_ + B_ * HID + B_ * 2) * sizeof(float);
  hipMemsetAsync(d_ws, 0, zbytes, stream);
  hipLaunchKernelGGL(k_wcast,  dim3(64),          dim3(256), 0, stream, Wq, Wk, Wv, Wo, wb);
  hipLaunchKernelGGL(k_kv_ctx, dim3(B_ * NSTRIP), dim3(256), 0, stream, x, wb + 16384, wb + 32768,
                     ctx_u, Zsum, fast ? xt : (short*)nullptr);
  if (fast)
    hipLaunchKernelGGL(k_q_attn_o, dim3(B_ * NSTRIP2), dim3(256), 0, stream,
                       xt, wb, wb + 49152, bo, ctx_u, Zsum, outp, stats);
  else
    hipLaunchKernelGGL(k_q_attn_o_legacy, dim3(B_ * NSTRIP), dim3(256), 0, stream,
                       x, wb, wb + 49152, bo, ctx_u, Zsum, outp, stats);
  hipLaunchKernelGGL(k_gnorm, dim3(B_ * 64), dim3(256), 0, stream, outp, stats, gnw, gnb);
}

// Round 2
// 268.184 us; speedup vs baseline: 1.1766x; 1.1766x over previous
//
#include <hip/hip_runtime.h>

// LinearAttention fused pipeline for MI355X (gfx950) — round 6.
// Post-mortem of r5: the swizzled-2D xt image caused 4x write amplification
// (16B scatter per 256B row -> WRITE_SIZE 122 MB) plus RMW fetch; K1 became
// HBM-bound at 105 us. Fix: xt is stored FRAGMENT-LINEAR
//   xt[tile][(ks*4+nt)*64 + lane][8 bf16]
// so every store/load/ds_read is lane-consecutive 16B (coalesced 1KB bursts,
// zero swizzle, conflict-free b128). Also: x->bf16 fragment conversion moves
// to a dedicated coalesced pass (k_xcast); K1 no longer reads f32 x at all —
// its 128 scalar ds_read + 128 f2bf per-lane repack is gone, LDS 68->52 KB
// (3 blocks/CU). K1 and K2 are now symmetric lean MFMA consumers of xt.
// Numerics bit-identical (same RNE f2bf, same MFMA accumulation order).
//
// ws: ctx_u[32][4][32][32] f32 | Z[32][128] f32 | stats[32][2] f32 |
//     wb 4x16384 bf16 | xt 2048 tiles x 16384 B (bf16 fragments)

#define B_   32
#define C_   128
#define N_   4096
#define H_   4
#define D_   32
#define HID  128
#define NB   64
#define TPB  4        // n-tiles per block (K1)
#define NSTRIP 16     // strips per batch, K1 (NSTRIP*TPB*NB == N_)
#define TPB2   2      // n-tiles per block (K2)
#define NSTRIP2 32    // strips per batch, K2
#define STV  72       // ek/v row stride (shorts)
#define STA  136      // eqT/attnT row stride (shorts)
#define SCT  40       // ctxT row stride (shorts)
#define SCALE 0.1767766952966369f
#define EPS  1e-5f

typedef __attribute__((ext_vector_type(8))) short short8;
typedef __attribute__((ext_vector_type(4))) short short4v;
typedef __attribute__((ext_vector_type(4))) float floatx4;

__device__ __forceinline__ short f2bf(float f) {   // RNE fp32 -> bf16
  unsigned u = __float_as_uint(f);
  u += 0x7FFFu + ((u >> 16) & 1u);
  return (short)(u >> 16);
}
__device__ __forceinline__ void gload_lds16(const float* g, void* l) {
  __builtin_amdgcn_global_load_lds(
      (const __attribute__((address_space(1))) unsigned int*)g,
      (__attribute__((address_space(3))) unsigned int*)l, 16, 0, 0);
}

// ---------------------------------------------------------------- K0: weights -> bf16
__global__ __launch_bounds__(256) void k_wcast(
    const float* __restrict__ Wq, const float* __restrict__ Wk,
    const float* __restrict__ Wv, const float* __restrict__ Wo,
    short* __restrict__ wb) {
  const int i = blockIdx.x * 256 + threadIdx.x;   // 0..16383, 4 elems each
  const float* srcs[4] = {Wq, Wk, Wv, Wo};
#pragma unroll
  for (int m = 0; m < 4; ++m) {
    floatx4 a = ((const floatx4*)srcs[m])[i];
    short4v s = { f2bf(a[0]), f2bf(a[1]), f2bf(a[2]), f2bf(a[3]) };
    ((short4v*)(wb + m * 16384))[i] = s;
  }
}

// ---------------------------------------------------------------- K0b: x -> bf16 fragment tiles
// One block per 128x64 tile. Thread (ks=tid>>6, L=tid&63) produces the 4
// nt-fragments frag(ks,nt,L)[j] = bf16(x[ks*32+q4*8+j][n0+nt*16+l15]).
// Reads: 64B-contiguous per 16-lane group. Stores: lane-consecutive 16B.
__global__ __launch_bounds__(256) void k_xcast(
    const float* __restrict__ x, short* __restrict__ xt) {
  const int tile = blockIdx.x;            // b*64 + tn
  const int b = tile >> 6, tn = tile & 63;
  const int tid = threadIdx.x;
  const int ks = tid >> 6, L = tid & 63, l15 = L & 15, q4 = L >> 4;
  const float* xb = x + (size_t)b * (C_ * N_) + (size_t)(ks * 32 + q4 * 8) * N_
                      + tn * NB + l15;
  short* xtb = xt + (size_t)tile * 8192 + (size_t)(ks * 256 + L) * 8;
#pragma unroll
  for (int nt = 0; nt < 4; ++nt) {
    short8 s;
#pragma unroll
    for (int j = 0; j < 8; ++j)
      s[j] = f2bf(xb[(size_t)j * N_ + nt * 16]);
    *(short8*)&xtb[nt * 512] = s;
  }
}

// ---------------------------------------------------------------- K1: k,v proj + ctx/Z
__global__ __launch_bounds__(256, 3) void k_kv_ctx(
    const short* __restrict__ xt, const short* __restrict__ Wkb,
    const short* __restrict__ Wvb, float* __restrict__ ctx_u,
    float* __restrict__ Zsum) {
  __shared__ short natx2[8192];          // 16 KB bf16 fragment tile
  __shared__ short ekbuf[C_ * STV];      // 18 KB
  __shared__ short vbuf [C_ * STV];      // 18 KB
  const int tid = threadIdx.x;
  const int w = tid >> 6, L = tid & 63, l15 = tid & 15, q4 = (tid & 63) >> 4;
  const int b = blockIdx.x / NSTRIP;
  const int strip = blockIdx.x % NSTRIP;

  // register-resident A-frags for both weights
  short8 ak[2][4], av[2][4];
#pragma unroll
  for (int mt = 0; mt < 2; ++mt)
#pragma unroll
    for (int ks = 0; ks < 4; ++ks) {
      ak[mt][ks] = *(const short8*)&Wkb[(w * 32 + mt * 16 + l15) * C_ + ks * 32 + q4 * 8];
      av[mt][ks] = *(const short8*)&Wvb[(w * 32 + mt * 16 + l15) * C_ + ks * 32 + q4 * 8];
    }

  const floatx4 z4 = {0.f, 0.f, 0.f, 0.f};
  floatx4 ca[2][2] = {{z4, z4}, {z4, z4}};   // ctx accumulator across tiles
  float zreg[2][4] = {{0.f,0.f,0.f,0.f},{0.f,0.f,0.f,0.f}};

  // stage tile 0 (linear 16 KB copy)
  {
    const float* src = (const float*)(xt + (size_t)(b * 64 + strip * TPB) * 8192);
#pragma unroll
    for (int i = 0; i < 4; ++i)
      gload_lds16(src + tid * 4 + i * 1024, (char*)natx2 + tid * 16 + i * 4096);
  }

  for (int t = 0; t < TPB; ++t) {
    __syncthreads();   // b1: stage(t) visible

    floatx4 acck[2][4], accv[2][4];
#pragma unroll
    for (int mt = 0; mt < 2; ++mt)
#pragma unroll
      for (int nt = 0; nt < 4; ++nt) { acck[mt][nt] = z4; accv[mt][nt] = z4; }

    // k and v GEMMs; B-frags are direct lane-linear ds_read_b128
#pragma unroll
    for (int ks = 0; ks < 4; ++ks) {
      short8 Bf[4];
#pragma unroll
      for (int nt = 0; nt < 4; ++nt)
        Bf[nt] = *(const short8*)&natx2[((ks * 4 + nt) * 64 + L) * 8];
#pragma unroll
      for (int mt = 0; mt < 2; ++mt)
#pragma unroll
        for (int nt = 0; nt < 4; ++nt) {
          acck[mt][nt] = __builtin_amdgcn_mfma_f32_16x16x32_bf16(ak[mt][ks], Bf[nt], acck[mt][nt], 0, 0, 0);
          accv[mt][nt] = __builtin_amdgcn_mfma_f32_16x16x32_bf16(av[mt][ks], Bf[nt], accv[mt][nt], 0, 0, 0);
        }
    }
    __syncthreads();   // b2: natx2 reads done -> restage allowed

    // prefetch stage(t+1) — flies during the wave-local phase below
    if (t + 1 < TPB) {
      const float* src = (const float*)(xt + (size_t)(b * 64 + strip * TPB + t + 1) * 8192);
#pragma unroll
      for (int i = 0; i < 4; ++i)
        gload_lds16(src + tid * 4 + i * 1024, (char*)natx2 + tid * 16 + i * 4096);
    }

    // exp(k) + Z partial accumulation in registers
#pragma unroll
    for (int mt = 0; mt < 2; ++mt)
#pragma unroll
      for (int nt = 0; nt < 4; ++nt)
#pragma unroll
        for (int r = 0; r < 4; ++r)
          acck[mt][nt][r] = __expf(acck[mt][nt][r]);
#pragma unroll
    for (int mt = 0; mt < 2; ++mt)
#pragma unroll
      for (int r = 0; r < 4; ++r)
        zreg[mt][r] += acck[mt][0][r] + acck[mt][1][r] + acck[mt][2][r] + acck[mt][3][r];

    // pack ek, v into wave-local LDS rows (in-wave DS ordering, no barrier)
#pragma unroll
    for (int mt = 0; mt < 2; ++mt)
#pragma unroll
      for (int nt = 0; nt < 4; ++nt)
#pragma unroll
        for (int r = 0; r < 4; ++r) {
          ekbuf[(w * 32 + mt * 16 + q4 * 4 + r) * STV + nt * 16 + l15] = f2bf(acck[mt][nt][r]);
          vbuf [(w * 32 + mt * 16 + q4 * 4 + r) * STV + nt * 16 + l15] = f2bf(accv[mt][nt][r]);
        }

    // ctx partial via MFMA (wave-local rows), accumulates across tiles
#pragma unroll
    for (int ks = 0; ks < 2; ++ks) {
      short8 ae[2], be[2];
#pragma unroll
      for (int mt = 0; mt < 2; ++mt)
        ae[mt] = *(const short8*)&ekbuf[(w * 32 + mt * 16 + l15) * STV + ks * 32 + q4 * 8];
#pragma unroll
      for (int nt = 0; nt < 2; ++nt)
        be[nt] = *(const short8*)&vbuf[(w * 32 + nt * 16 + l15) * STV + ks * 32 + q4 * 8];
#pragma unroll
      for (int mt = 0; mt < 2; ++mt)
#pragma unroll
        for (int nt = 0; nt < 2; ++nt)
          ca[mt][nt] = __builtin_amdgcn_mfma_f32_16x16x32_bf16(ae[mt], be[nt], ca[mt][nt], 0, 0, 0);
    }
  }

  // Z: reduce over l15, one atomic per row
#pragma unroll
  for (int mt = 0; mt < 2; ++mt)
#pragma unroll
    for (int r = 0; r < 4; ++r) {
      float s = zreg[mt][r];
      s += __shfl_xor(s, 1); s += __shfl_xor(s, 2);
      s += __shfl_xor(s, 4); s += __shfl_xor(s, 8);
      if (l15 == 0) atomicAdd(&Zsum[b * HID + w * 32 + mt * 16 + q4 * 4 + r], s);
    }

  // ctx atomics (once per block)
  float* cb = &ctx_u[((size_t)b * H_ + w) * (D_ * D_)];
#pragma unroll
  for (int mt = 0; mt < 2; ++mt)
#pragma unroll
    for (int nt = 0; nt < 2; ++nt)
#pragma unroll
      for (int r = 0; r < 4; ++r)
        atomicAdd(&cb[(mt * 16 + q4 * 4 + r) * D_ + nt * 16 + l15], ca[mt][nt][r]);
}

// ---------------------------------------------------------------- K2: q proj + attn + Wo + stats
__global__ __launch_bounds__(256, 3) void k_q_attn_o(
    const short* __restrict__ xt, const short* __restrict__ Wqb,
    const short* __restrict__ Wob, const float* __restrict__ bo,
    const float* __restrict__ ctx_u, const float* __restrict__ Zsum,
    float* __restrict__ outp, float* __restrict__ stats) {
  __shared__ short natx2[8192];       // 16 KB bf16 fragment tile
  __shared__ short qat[NB * STA];     // eq^T then attn^T, 17 KB
  __shared__ short ctxT[HID * SCT];   // 10 KB
  const int tid = threadIdx.x;
  const int w = tid >> 6, L = tid & 63, l15 = tid & 15, q4 = (tid & 63) >> 4;
  const int b = blockIdx.x / NSTRIP2;
  const int strip = blockIdx.x % NSTRIP2;

  // stage tile 0 (linear 16 KB copy), then fill ctxT while loads fly
  {
    const float* src = (const float*)(xt + (size_t)(b * 64 + strip * TPB2) * 8192);
#pragma unroll
    for (int i = 0; i < 4; ++i)
      gload_lds16(src + tid * 4 + i * 1024, (char*)natx2 + tid * 16 + i * 4096);
  }
#pragma unroll
  for (int i = 0; i < 16; ++i) {
    const int idx = tid + i * 256;               // h*1024 + d*32 + e
    float v = ctx_u[(size_t)b * (H_ * D_ * D_) + idx] *
              __builtin_amdgcn_rcpf(Zsum[b * HID + (idx >> 5)]);
    ctxT[((idx >> 10) * 32 + (idx & 31)) * SCT + ((idx >> 5) & 31)] = f2bf(v);
  }

  // register-resident A-frags for Wq and Wo
  short8 aq[2][4], ao[2][4];
#pragma unroll
  for (int mt = 0; mt < 2; ++mt)
#pragma unroll
    for (int ks = 0; ks < 4; ++ks) {
      aq[mt][ks] = *(const short8*)&Wqb[(w * 32 + mt * 16 + l15) * C_ + ks * 32 + q4 * 8];
      ao[mt][ks] = *(const short8*)&Wob[(w * 32 + mt * 16 + l15) * HID + ks * 32 + q4 * 8];
    }

  const floatx4 z4 = {0.f, 0.f, 0.f, 0.f};
  float s1 = 0.f, s2 = 0.f;

  for (int t = 0; t < TPB2; ++t) {
    const int n0 = (strip * TPB2 + t) * NB;
    __syncthreads();   // b1: stage(t) + (t==0) ctxT visible

    // q = Wq @ x — B-frags are direct lane-linear ds_read_b128, no converts
    floatx4 acc[2][4];
#pragma unroll
    for (int mt = 0; mt < 2; ++mt)
#pragma unroll
      for (int nt = 0; nt < 4; ++nt) acc[mt][nt] = z4;
#pragma unroll
    for (int ks = 0; ks < 4; ++ks) {
      short8 Bf[4];
#pragma unroll
      for (int nt = 0; nt < 4; ++nt)
        Bf[nt] = *(const short8*)&natx2[((ks * 4 + nt) * 64 + L) * 8];
#pragma unroll
      for (int mt = 0; mt < 2; ++mt)
#pragma unroll
        for (int nt = 0; nt < 4; ++nt)
          acc[mt][nt] = __builtin_amdgcn_mfma_f32_16x16x32_bf16(aq[mt][ks], Bf[nt], acc[mt][nt], 0, 0, 0);
    }
    __syncthreads();   // b2: natx2 reads done -> restage allowed

    // prefetch stage(t+1)
    if (t + 1 < TPB2) {
      const float* src = (const float*)(xt + (size_t)(b * 64 + strip * TPB2 + t + 1) * 8192);
#pragma unroll
      for (int i = 0; i < 4; ++i)
        gload_lds16(src + tid * 4 + i * 1024, (char*)natx2 + tid * 16 + i * 4096);
    }

    // exp(q); per-column softmax denom via shuffle
#pragma unroll
    for (int mt = 0; mt < 2; ++mt)
#pragma unroll
      for (int nt = 0; nt < 4; ++nt)
#pragma unroll
        for (int r = 0; r < 4; ++r)
          acc[mt][nt][r] = __expf(acc[mt][nt][r]);
    float inv[4];
#pragma unroll
    for (int nt = 0; nt < 4; ++nt) {
      float s = 0.f;
#pragma unroll
      for (int mt = 0; mt < 2; ++mt)
#pragma unroll
        for (int r = 0; r < 4; ++r) s += acc[mt][nt][r];
      s += __shfl_xor(s, 16); s += __shfl_xor(s, 32);
      inv[nt] = SCALE * __builtin_amdgcn_rcpf(s);
    }

    // scaled eq^T into qat (wave-local columns)
#pragma unroll
    for (int mt = 0; mt < 2; ++mt)
#pragma unroll
      for (int nt = 0; nt < 4; ++nt) {
        short4v pk = { f2bf(acc[mt][nt][0] * inv[nt]), f2bf(acc[mt][nt][1] * inv[nt]),
                       f2bf(acc[mt][nt][2] * inv[nt]), f2bf(acc[mt][nt][3] * inv[nt]) };
        *(short4v*)&qat[(nt * 16 + l15) * STA + w * 32 + mt * 16 + q4 * 4] = pk;
      }

    // attn: out[e][n] = sum_d ctxT[e][d] * eq[d][n]   (wave-local)
    {
      floatx4 aacc[2][4];
#pragma unroll
      for (int mt = 0; mt < 2; ++mt)
#pragma unroll
        for (int nt = 0; nt < 4; ++nt) aacc[mt][nt] = z4;
      short8 ae[2];
#pragma unroll
      for (int mt = 0; mt < 2; ++mt)
        ae[mt] = *(const short8*)&ctxT[(w * 32 + mt * 16 + l15) * SCT + q4 * 8];
#pragma unroll
      for (int nt = 0; nt < 4; ++nt) {
        short8 bq = *(const short8*)&qat[(nt * 16 + l15) * STA + w * 32 + q4 * 8];
#pragma unroll
        for (int mt = 0; mt < 2; ++mt)
          aacc[mt][nt] = __builtin_amdgcn_mfma_f32_16x16x32_bf16(ae[mt], bq, aacc[mt][nt], 0, 0, 0);
      }
      // attn^T over eq^T (same wave-local columns)
#pragma unroll
      for (int nt = 0; nt < 4; ++nt)
#pragma unroll
        for (int mt = 0; mt < 2; ++mt) {
          short4v pk = { f2bf(aacc[mt][nt][0]), f2bf(aacc[mt][nt][1]),
                         f2bf(aacc[mt][nt][2]), f2bf(aacc[mt][nt][3]) };
          *(short4v*)&qat[(nt * 16 + l15) * STA + w * 32 + mt * 16 + q4 * 4] = pk;
        }
    }
    __syncthreads();   // b3: attn^T visible to all waves

    // out_pre = Wo @ attn + bo
    floatx4 oacc[2][4];
#pragma unroll
    for (int mt = 0; mt < 2; ++mt)
#pragma unroll
      for (int nt = 0; nt < 4; ++nt) oacc[mt][nt] = z4;
#pragma unroll
    for (int ks = 0; ks < 4; ++ks) {
      short8 bf8[4];
#pragma unroll
      for (int nt = 0; nt < 4; ++nt)
        bf8[nt] = *(const short8*)&qat[(nt * 16 + l15) * STA + ks * 32 + q4 * 8];
#pragma unroll
      for (int mt = 0; mt < 2; ++mt)
#pragma unroll
        for (int nt = 0; nt < 4; ++nt)
          oacc[mt][nt] = __builtin_amdgcn_mfma_f32_16x16x32_bf16(ao[mt][ks], bf8[nt], oacc[mt][nt], 0, 0, 0);
    }

    // epilogue: +bo, store, accumulate stats in registers
#pragma unroll
    for (int mt = 0; mt < 2; ++mt) {
      const int rowbase = w * 32 + mt * 16 + q4 * 4;
      const floatx4 bo4 = *(const floatx4*)&bo[rowbase];
#pragma unroll
      for (int nt = 0; nt < 4; ++nt) {
        const int n = n0 + nt * 16 + l15;
#pragma unroll
        for (int r = 0; r < 4; ++r) {
          float vv = oacc[mt][nt][r] + bo4[r];
          outp[(size_t)b * (C_ * N_) + (size_t)(rowbase + r) * N_ + n] = vv;
          s1 += vv; s2 += vv * vv;
        }
      }
    }
  }

  // stats: wave reduce + one atomic pair per wave
#pragma unroll
  for (int m = 1; m < 64; m <<= 1) {
    s1 += __shfl_xor(s1, m);
    s2 += __shfl_xor(s2, m);
  }
  if ((tid & 63) == 0) {
    atomicAdd(&stats[b * 2 + 0], s1);
    atomicAdd(&stats[b * 2 + 1], s2);
  }
}

// ---------------------------------------------------------------- K3: GroupNorm
__global__ __launch_bounds__(256) void k_gnorm(
    float* __restrict__ outp, const float* __restrict__ stats,
    const float* __restrict__ gnw, const float* __restrict__ gnb) {
  const int b = blockIdx.x >> 6;
  const int blk = blockIdx.x & 63;
  const float M = (float)(C_ * N_);
  const float mu = stats[b * 2 + 0] / M;
  const float var = stats[b * 2 + 1] / M - mu * mu;
  const float rs = rsqrtf(var + EPS);
  floatx4* p = (floatx4*)(outp + (size_t)b * (C_ * N_) + (size_t)blk * 8192);
  const int tid = threadIdx.x;
#pragma unroll
  for (int i = 0; i < 8; ++i) {
    const int idx = tid + i * 256;
    const int fl = blk * 8192 + idx * 4;
    const int c = fl >> 12;
    const float wgt = gnw[c] * rs;
    const float bia = gnb[c] - mu * wgt;
    floatx4 v = p[idx];
    v[0] = v[0] * wgt + bia;
    v[1] = v[1] * wgt + bia;
    v[2] = v[2] * wgt + bia;
    v[3] = v[3] * wgt + bia;
    p[idx] = v;
  }
}

// ---------------------------------------------------------------- launch
extern "C" void kernel_launch(void* const* d_in, const int* in_sizes, int n_in,
                              void* d_out, int out_size, void* d_ws, size_t ws_size,
                              hipStream_t stream) {
  (void)in_sizes; (void)n_in; (void)out_size; (void)ws_size;
  const float* x   = (const float*)d_in[0];
  const float* Wq  = (const float*)d_in[1];
  const float* Wk  = (const float*)d_in[2];
  const float* Wv  = (const float*)d_in[3];
  const float* Wo  = (const float*)d_in[4];
  const float* bo  = (const float*)d_in[5];
  const float* gnw = (const float*)d_in[6];
  const float* gnb = (const float*)d_in[7];
  float* outp  = (float*)d_out;
  float* ctx_u = (float*)d_ws;                       // 131072 f
  float* Zsum  = ctx_u + B_ * H_ * D_ * D_;          // 4096 f
  float* stats = Zsum + B_ * HID;                    // 64 f
  short* wb    = (short*)(stats + B_ * 2);           // 4 x 16384 bf16
  short* xt    = (short*)((char*)d_ws + 672000);     // 2048 tiles x 16384 B
  const size_t zbytes = (size_t)(B_ * H_ * D_ * D_ + B_ * HID + B_ * 2) * sizeof(float);
  hipMemsetAsync(d_ws, 0, zbytes, stream);
  hipLaunchKernelGGL(k_wcast,    dim3(64),           dim3(256), 0, stream, Wq, Wk, Wv, Wo, wb);
  hipLaunchKernelGGL(k_xcast,    dim3(B_ * 64),      dim3(256), 0, stream, x, xt);
  hipLaunchKernelGGL(k_kv_ctx,   dim3(B_ * NSTRIP),  dim3(256), 0, stream, xt, wb + 16384, wb + 32768, ctx_u, Zsum);
  hipLaunchKernelGGL(k_q_attn_o, dim3(B_ * NSTRIP2), dim3(256), 0, stream, xt, wb, wb + 49152, bo, ctx_u, Zsum, outp, stats);
  hipLaunchKernelGGL(k_gnorm,    dim3(B_ * 64),      dim3(256), 0, stream, outp, stats, gnw, gnb);
}